// Round 3
// baseline (71.289 us; speedup 1.0000x reference)
//
#include <hip/hip_runtime.h>
#include <hip/hip_bf16.h>

typedef __bf16 v8bf __attribute__((ext_vector_type(8)));
typedef float f32x16 __attribute__((ext_vector_type(16)));
typedef unsigned int uint;
typedef unsigned short ushort;

__device__ inline f32x16 zero16() {
  f32x16 z;
#pragma unroll
  for (int i = 0; i < 16; i++) z[i] = 0.f;
  return z;
}

__device__ inline uint pack_bf16(float a, float b) {
  union { __bf16 h[2]; uint u; } c;
  c.h[0] = (__bf16)a;
  c.h[1] = (__bf16)b;
  return c.u;
}

// ---------------------------------------------------------------------------
// Kernel 0: Wt[192][1024] bf16 = transpose of [Wq|Wk|Wv], coalesced via LDS.
// 48 blocks = 3 mats x 16 c-tiles; tile 64c x 64h.
// ---------------------------------------------------------------------------
__global__ void prep_wt(const float* __restrict__ Wq, const float* __restrict__ Wk,
                        const float* __restrict__ Wv, __bf16* __restrict__ Wt) {
  __shared__ __bf16 tile[64][74];  // [c_local][h], stride 74 breaks 16-row bank alias
  const int mat = blockIdx.x >> 4;
  const int c0 = (blockIdx.x & 15) * 64;
  const float* src = (mat == 0) ? Wq : (mat == 1) ? Wk : Wv;
  const int t = threadIdx.x;      // 256 threads
  const int r = t >> 2;           // c_local 0..63
  const int ch = (t & 3) * 16;    // h chunk
  const float4* s4 = (const float4*)(src + (size_t)(c0 + r) * 64 + ch);
#pragma unroll
  for (int j = 0; j < 4; j++) {
    float4 f = s4[j];
    tile[r][ch + 4 * j + 0] = (__bf16)f.x;
    tile[r][ch + 4 * j + 1] = (__bf16)f.y;
    tile[r][ch + 4 * j + 2] = (__bf16)f.z;
    tile[r][ch + 4 * j + 3] = (__bf16)f.w;
  }
  __syncthreads();
  const int h = t >> 2;           // 0..63
  const int cc = (t & 3) * 16;    // c chunk
  union { __bf16 o[16]; uint4 u[2]; } pk;
#pragma unroll
  for (int j = 0; j < 16; j++) pk.o[j] = tile[cc + j][h];
  uint4* dst = (uint4*)(Wt + (size_t)(mat * 64 + h) * 1024 + c0 + cc);
  dst[0] = pk.u[0];
  dst[1] = pk.u[1];
}

// ---------------------------------------------------------------------------
// Kernel 1: KQV[32768][192] = x[32768][1024] * W  (bf16 MFMA, fp32 accum)
// 256 blocks x 512 threads; block tile 128x192, wave tile 32x96, BK=64.
// Reg+LDS double-buffered: loads for step t+1 issued before MFMA(t).
// ---------------------------------------------------------------------------
__launch_bounds__(512, 2)
__global__ void proj_kernel(const float* __restrict__ x, const uint4* __restrict__ Wt4,
                            __bf16* __restrict__ KQV) {
  __shared__ char lds[81920];  // 2 x (A 16KB + W 24KB)
  char* A0 = lds;          char* W0 = lds + 16384;
  char* A1 = lds + 40960;  char* W1 = lds + 57344;

  const int tid = threadIdx.x;
  const int lane = tid & 63;
  const int wave = tid >> 6;  // 0..7
  const int wm = wave >> 1;   // 0..3 (M)
  const int wn = wave & 1;    // 0..1 (N)
  const int row0 = blockIdx.x * 128;
  const int ar0 = tid >> 3;   // staging row (i=0); i=1 adds 64
  const int ac0 = tid & 7;    // staging col chunk

  f32x16 acc[3];
#pragma unroll
  for (int i = 0; i < 3; i++) acc[i] = zero16();

  float4 fa[4]; uint4 fw[3];
  float4 ga[4]; uint4 gw[3];

  auto loadA = [&](int k0, float4* f) {
    const float4* s0 = (const float4*)(x + (size_t)(row0 + ar0) * 1024 + k0 + ac0 * 8);
    const float4* s1 = (const float4*)(x + (size_t)(row0 + ar0 + 64) * 1024 + k0 + ac0 * 8);
    f[0] = s0[0]; f[1] = s0[1]; f[2] = s1[0]; f[3] = s1[1];
  };
  auto loadW = [&](int k0, uint4* w) {
#pragma unroll
    for (int i = 0; i < 3; i++)
      w[i] = Wt4[(size_t)((tid >> 3) + i * 64) * 128 + (k0 >> 3) + ac0];
  };
  auto stage = [&](const float4* f, const uint4* w, char* Alds, char* Wlds) {
#pragma unroll
    for (int i = 0; i < 2; i++) {
      int r = ar0 + i * 64;
      float4 f0 = f[2 * i], f1 = f[2 * i + 1];
      union { __bf16 h[8]; v8bf v; } cv;
      cv.h[0] = (__bf16)f0.x; cv.h[1] = (__bf16)f0.y;
      cv.h[2] = (__bf16)f0.z; cv.h[3] = (__bf16)f0.w;
      cv.h[4] = (__bf16)f1.x; cv.h[5] = (__bf16)f1.y;
      cv.h[6] = (__bf16)f1.z; cv.h[7] = (__bf16)f1.w;
      *(v8bf*)(Alds + r * 128 + ((ac0 * 16) ^ ((r & 7) << 4))) = cv.v;
    }
#pragma unroll
    for (int i = 0; i < 3; i++) {
      int n = (tid >> 3) + i * 64;
      *(uint4*)(Wlds + n * 128 + ((ac0 * 16) ^ ((n & 7) << 4))) = w[i];
    }
  };
  auto mma = [&](const char* Alds, const char* Wlds) {
#pragma unroll
    for (int ks = 0; ks < 4; ks++) {
      int kbyte = ks * 32 + ((lane >> 5) << 4);
      int arow = wm * 32 + (lane & 31);
      v8bf a = *(const v8bf*)(Alds + arow * 128 + (kbyte ^ ((arow & 7) << 4)));
#pragma unroll
      for (int nf = 0; nf < 3; nf++) {
        int brow = wn * 96 + nf * 32 + (lane & 31);
        v8bf b = *(const v8bf*)(Wlds + brow * 128 + (kbyte ^ ((brow & 7) << 4)));
        acc[nf] = __builtin_amdgcn_mfma_f32_32x32x16_bf16(a, b, acc[nf], 0, 0, 0);
      }
    }
  };

  loadA(0, fa);
  loadW(0, fw);
  for (int k0 = 0; k0 < 1024; k0 += 128) {
    // step t (even): buffer 0
    stage(fa, fw, A0, W0);
    __syncthreads();
    loadA(k0 + 64, ga);
    loadW(k0 + 64, gw);
    __builtin_amdgcn_sched_barrier(0);  // keep load issue ahead of MFMA
    mma(A0, W0);
    // step t+1 (odd): buffer 1
    stage(ga, gw, A1, W1);
    __syncthreads();
    if (k0 + 128 < 1024) {
      loadA(k0 + 128, fa);
      loadW(k0 + 128, fw);
    }
    __builtin_amdgcn_sched_barrier(0);
    mma(A1, W1);
  }

  // epilogue: write bf16 KQV
#pragma unroll
  for (int nf = 0; nf < 3; nf++) {
#pragma unroll
    for (int r = 0; r < 16; r++) {
      int row = wm * 32 + (r & 3) + ((r >> 2) << 3) + ((lane >> 5) << 2);
      int col = wn * 96 + nf * 32 + (lane & 31);
      KQV[(size_t)(row0 + row) * 192 + col] = (__bf16)acc[nf][r];
    }
  }
}

// ---------------------------------------------------------------------------
// Kernel 2: causal attention per batch. 256 blocks (= 128 batches x 2 halves)
// x 256 threads (4 waves). Wave owns 32 q-rows. Swapped QK^T -> lane-local softmax.
// ---------------------------------------------------------------------------
__launch_bounds__(256, 1)
__global__ void attn_kernel(const __bf16* __restrict__ KQV, float* __restrict__ out) {
  __shared__ uint4 lds4[81920 / 16];  // K:[256][64] 32KB | Vt:[64][256] 32KB | Q:[128][64] 16KB
  char* Klds = (char*)lds4;
  char* Vlds = (char*)lds4 + 32768;
  char* Qlds = (char*)lds4 + 65536;

  const int tid = threadIdx.x;
  const int lane = tid & 63;
  const int wave = tid >> 6;  // 0..3
  const int b = blockIdx.x >> 1;
  const int half = blockIdx.x & 1;
  const int bt0 = half * 128;
  const size_t base = (size_t)b * 256 * 192;

  // stage K rows (cols 64..127), swizzled row-major [s][h]
  {
    int s = tid;
    const uint4* src = (const uint4*)(KQV + base + (size_t)s * 192 + 64);
#pragma unroll
    for (int i = 0; i < 8; i++) {
      uint4 v = src[i];
      int byte = s * 128 + ((i * 16) ^ ((s & 7) << 4));
      *(uint4*)(Klds + byte) = v;
    }
  }
  // stage V transposed: Vt[h][s], swizzled (scatter b16 writes)
  {
    int s = tid;
    const uint4* src = (const uint4*)(KQV + base + (size_t)s * 192 + 128);
#pragma unroll
    for (int i = 0; i < 8; i++) {
      uint4 v = src[i];
      const ushort* e = (const ushort*)&v;
#pragma unroll
      for (int j = 0; j < 8; j++) {
        int h = i * 8 + j;
        int byte = h * 512 + ((s * 2) ^ ((h & 7) << 4));
        *(ushort*)(Vlds + byte) = e[j];
      }
    }
  }
  // stage Q rows (block's 128 t-rows, cols 0..63)
#pragma unroll
  for (int i = 0; i < 4; i++) {
    int c = tid + i * 256;
    int r = c >> 3, cc = c & 7;
    uint4 v = *(const uint4*)(KQV + base + (size_t)(bt0 + r) * 192 + cc * 8);
    int byte = r * 128 + ((cc * 16) ^ ((r & 7) << 4));
    *(uint4*)(Qlds + byte) = v;
  }
  __syncthreads();

  const int t0 = bt0 + wave * 32;
  const int tg = t0 + (lane & 31);   // this lane's q row
  const int nf = (t0 >> 5) + 1;      // causal: s frags needed

  // S^T = K * Q^T : D[s][t], col = t (lane-local q-row)
  f32x16 sacc[8];
#pragma unroll
  for (int sf = 0; sf < 8; sf++) {
    f32x16 sv = zero16();
    if (sf < nf) {
#pragma unroll
      for (int ks = 0; ks < 4; ks++) {
        int kbyte = ks * 32 + ((lane >> 5) << 4);
        int krow = sf * 32 + (lane & 31);
        v8bf a = *(const v8bf*)(Klds + krow * 128 + (kbyte ^ ((krow & 7) << 4)));
        int qrow = wave * 32 + (lane & 31);
        v8bf bq = *(const v8bf*)(Qlds + qrow * 128 + (kbyte ^ ((qrow & 7) << 4)));
        sv = __builtin_amdgcn_mfma_f32_32x32x16_bf16(a, bq, sv, 0, 0, 0);
      }
    }
    sacc[sf] = sv;
  }

  // scale + causal mask + row max (per-lane, rows are lane-local in t)
  float m = -1e30f;
#pragma unroll
  for (int sf = 0; sf < 8; sf++) {
    if (sf < nf) {
#pragma unroll
      for (int r = 0; r < 16; r++) {
        int sg = sf * 32 + (r & 3) + ((r >> 2) << 3) + ((lane >> 5) << 2);
        float v = sacc[sf][r] * 0.125f;
        v = (sg > tg) ? -1e30f : v;
        sacc[sf][r] = v;
        m = fmaxf(m, v);
      }
    }
  }
  m = fmaxf(m, __shfl_xor(m, 32, 64));
  float l = 0.f;
#pragma unroll
  for (int sf = 0; sf < 8; sf++) {
    if (sf < nf) {
#pragma unroll
      for (int r = 0; r < 16; r++) {
        float p = __expf(sacc[sf][r] - m);
        sacc[sf][r] = p;
        l += p;
      }
    }
  }
  l += __shfl_xor(l, 32, 64);
  float inv = 1.0f / l;

  // O = P * V : P as A-operand (built in-register via packed bf16 + shfl_xor 32)
  f32x16 oacc[2];
  oacc[0] = zero16();
  oacc[1] = zero16();
  const bool hiLane = (lane >= 32);
#pragma unroll
  for (int sf = 0; sf < 8; sf++) {
    if (sf < nf) {
      uint w[8], ow[8];
#pragma unroll
      for (int q = 0; q < 4; q++) {
        w[2 * q]     = pack_bf16(sacc[sf][4 * q] * inv,     sacc[sf][4 * q + 1] * inv);
        w[2 * q + 1] = pack_bf16(sacc[sf][4 * q + 2] * inv, sacc[sf][4 * q + 3] * inv);
      }
#pragma unroll
      for (int i = 0; i < 8; i++) ow[i] = (uint)__shfl_xor((int)w[i], 32, 64);
#pragma unroll
      for (int ks = 0; ks < 2; ks++) {
        int bse = 4 * ks;
        union { uint u[4]; v8bf v; } A;
        A.u[0] = hiLane ? ow[bse + 2] : w[bse + 0];
        A.u[1] = hiLane ? ow[bse + 3] : w[bse + 1];
        A.u[2] = hiLane ? w[bse + 2] : ow[bse + 0];
        A.u[3] = hiLane ? w[bse + 3] : ow[bse + 1];
        int sbyte0 = (sf * 32 + ks * 16) * 2 + ((lane >> 5) << 4);
#pragma unroll
        for (int hf = 0; hf < 2; hf++) {
          int vrow = hf * 32 + (lane & 31);
          v8bf bv = *(const v8bf*)(Vlds + vrow * 512 + (sbyte0 ^ ((vrow & 7) << 4)));
          oacc[hf] = __builtin_amdgcn_mfma_f32_32x32x16_bf16(A.v, bv, oacc[hf], 0, 0, 0);
        }
      }
    }
  }

  // write out fp32: D col = h, row pattern = t
#pragma unroll
  for (int hf = 0; hf < 2; hf++) {
#pragma unroll
    for (int r = 0; r < 16; r++) {
      int t = t0 + (r & 3) + ((r >> 2) << 3) + ((lane >> 5) << 2);
      int h = hf * 32 + (lane & 31);
      out[((size_t)b * 256 + t) * 64 + h] = oacc[hf][r];
    }
  }
}

// ---------------------------------------------------------------------------
extern "C" void kernel_launch(void* const* d_in, const int* in_sizes, int n_in,
                              void* d_out, int out_size, void* d_ws, size_t ws_size,
                              hipStream_t stream) {
  const float* x  = (const float*)d_in[0];
  const float* Wk = (const float*)d_in[1];
  const float* Wq = (const float*)d_in[2];
  const float* Wv = (const float*)d_in[3];
  float* out = (float*)d_out;

  // workspace layout: KQV bf16 [32768][192] (12.58 MB), then Wt bf16 [192][1024]
  __bf16* KQV = (__bf16*)d_ws;
  __bf16* Wt  = (__bf16*)((char*)d_ws + (size_t)32768 * 192 * 2);

  prep_wt<<<48, 256, 0, stream>>>(Wq, Wk, Wv, Wt);
  proj_kernel<<<256, 512, 0, stream>>>(x, (const uint4*)Wt, KQV);
  attn_kernel<<<256, 256, 0, stream>>>(KQV, out);
}

// Round 4
// 65.432 us; speedup vs baseline: 1.0895x; 1.0895x over previous
//
#include <hip/hip_runtime.h>
#include <hip/hip_bf16.h>

typedef __bf16 v8bf __attribute__((ext_vector_type(8)));
typedef float f32x16 __attribute__((ext_vector_type(16)));
typedef unsigned int uint;
typedef unsigned short ushort;

#define GLOAD16(gsrc, ldst)                                                       \
  __builtin_amdgcn_global_load_lds(                                               \
      (const __attribute__((address_space(1))) unsigned int*)(gsrc),              \
      (__attribute__((address_space(3))) unsigned int*)(ldst), 16, 0, 0)

__device__ inline f32x16 zero16() {
  f32x16 z;
#pragma unroll
  for (int i = 0; i < 16; i++) z[i] = 0.f;
  return z;
}

__device__ inline uint pack_bf16(float a, float b) {
  union { __bf16 h[2]; uint u; } c;
  c.h[0] = (__bf16)a;
  c.h[1] = (__bf16)b;
  return c.u;
}

// ---------------------------------------------------------------------------
// Kernel 0: Wt_s = transpose of [Wq|Wk|Wv] -> bf16, PRE-SWIZZLED:
// element (n,k) stored at byte n*2048 + (k>>6)*128 + (((k&63)*2) ^ ((n&7)<<4)).
// A linear global_load_lds copy of a 128B k-chunk then lands the XOR-swizzle
// in LDS for conflict-reduced ds_read_b128 (rule: both-sides-or-neither).
// 48 blocks = 3 mats x 16 c-tiles; tile 64c x 64h.
// ---------------------------------------------------------------------------
__global__ void prep_wt(const float* __restrict__ Wq, const float* __restrict__ Wk,
                        const float* __restrict__ Wv, char* __restrict__ Wt_s) {
  __shared__ __bf16 tile[64][74];
  const int mat = blockIdx.x >> 4;
  const int c0 = (blockIdx.x & 15) * 64;  // element offset along C
  const float* src = (mat == 0) ? Wq : (mat == 1) ? Wk : Wv;
  const int t = threadIdx.x;  // 256 threads
  {
    const int r = t >> 2;         // c_local 0..63
    const int ch = (t & 3) * 16;  // h chunk
    const float4* s4 = (const float4*)(src + (size_t)(c0 + r) * 64 + ch);
#pragma unroll
    for (int j = 0; j < 4; j++) {
      float4 f = s4[j];
      tile[r][ch + 4 * j + 0] = (__bf16)f.x;
      tile[r][ch + 4 * j + 1] = (__bf16)f.y;
      tile[r][ch + 4 * j + 2] = (__bf16)f.z;
      tile[r][ch + 4 * j + 3] = (__bf16)f.w;
    }
  }
  __syncthreads();
  const int h = t >> 2;          // 0..63
  const int cc = (t & 3) * 16;   // element offset within 64-elem chunk
  union { __bf16 o[16]; uint4 u[2]; } pk;
#pragma unroll
  for (int j = 0; j < 16; j++) pk.o[j] = tile[cc + j][h];
  const int n = mat * 64 + h;
  char* base = Wt_s + (size_t)n * 2048 + (c0 >> 6) * 128;
  const int bc = cc * 2;
  *(uint4*)(base + ((bc) ^ ((n & 7) << 4))) = pk.u[0];
  *(uint4*)(base + ((bc + 16) ^ ((n & 7) << 4))) = pk.u[1];
}

// ---------------------------------------------------------------------------
// Kernel 1: KQV[32768][192] = x * W. 512 blocks x 256 threads.
// Block tile 64x192; wave (wm=wave>>1, wn=wave&1) tile 32x96; BK=64.
// A: global -> registers directly (no LDS). W: LDS double-buffer via
// global_load_lds from pre-swizzled Wt_s. One barrier per K-step.
// ---------------------------------------------------------------------------
__launch_bounds__(256, 2)
__global__ void proj_kernel(const float* __restrict__ x, const char* __restrict__ Wt_s,
                            __bf16* __restrict__ KQV) {
  __shared__ char Wlds[2][24576];  // [192 rows][128 B] each, swizzle baked in

  const int tid = threadIdx.x;
  const int lane = tid & 63;
  const int wave = tid >> 6;  // 0..3
  const int wm = wave >> 1;
  const int wn = wave & 1;
  const int row0 = blockIdx.x * 64;
  const int arow = row0 + wm * 32 + (lane & 31);
  // lane's A pointer: element base = arow*1024 + (lane>>5)*8
  const float4* xp = (const float4*)(x + (size_t)arow * 1024 + ((lane >> 5) << 3));
  // W staging source (per lane), dest (wave-uniform; HW adds lane*16)
  const char* wsrc = Wt_s + (size_t)(wave * 8 + (lane >> 3)) * 2048 + (lane & 7) * 16;
  const int wdo = wave * 1024;

  f32x16 acc[3];
#pragma unroll
  for (int i = 0; i < 3; i++) acc[i] = zero16();

  float4 aA[8], aB[8];

#define LOADA(a, t)                                                               \
  {                                                                               \
    _Pragma("unroll") for (int ks = 0; ks < 4; ks++) {                            \
      a[2 * ks] = xp[(t) * 16 + ks * 4];                                          \
      a[2 * ks + 1] = xp[(t) * 16 + ks * 4 + 1];                                  \
    }                                                                             \
  }

#define GLOADW(b, t)                                                              \
  {                                                                               \
    _Pragma("unroll") for (int i = 0; i < 6; i++) {                               \
      GLOAD16(wsrc + (size_t)i * 65536 + (t) * 128, &Wlds[b][i * 4096 + wdo]);    \
    }                                                                             \
  }

#define MMA(b, a)                                                                 \
  {                                                                               \
    _Pragma("unroll") for (int ks = 0; ks < 4; ks++) {                            \
      union { __bf16 h[8]; v8bf v; } av;                                          \
      float4 a0 = a[2 * ks], a1 = a[2 * ks + 1];                                  \
      av.h[0] = (__bf16)a0.x; av.h[1] = (__bf16)a0.y;                             \
      av.h[2] = (__bf16)a0.z; av.h[3] = (__bf16)a0.w;                             \
      av.h[4] = (__bf16)a1.x; av.h[5] = (__bf16)a1.y;                             \
      av.h[6] = (__bf16)a1.z; av.h[7] = (__bf16)a1.w;                             \
      int kbyte = ks * 32 + ((lane >> 5) << 4);                                   \
      _Pragma("unroll") for (int nf = 0; nf < 3; nf++) {                          \
        int brow = wn * 96 + nf * 32 + (lane & 31);                               \
        v8bf bv = *(const v8bf*)(&Wlds[b][brow * 128 + (kbyte ^ ((brow & 7) << 4))]); \
        acc[nf] = __builtin_amdgcn_mfma_f32_32x32x16_bf16(av.v, bv, acc[nf], 0, 0, 0); \
      }                                                                           \
    }                                                                             \
  }

  LOADA(aA, 0);
  GLOADW(0, 0);
  for (int t = 0; t < 16; t += 2) {
    __syncthreads();  // drains W(t)->buf0 and A(t)->aA
    LOADA(aB, t + 1);
    GLOADW(1, t + 1);
    MMA(0, aA);
    __syncthreads();  // drains W(t+1)->buf1 and aB
    if (t + 2 < 16) {
      LOADA(aA, t + 2);
      GLOADW(0, t + 2);
    }
    MMA(1, aB);
  }

  // epilogue: write bf16 KQV
#pragma unroll
  for (int nf = 0; nf < 3; nf++) {
#pragma unroll
    for (int r = 0; r < 16; r++) {
      int row = row0 + wm * 32 + (r & 3) + ((r >> 2) << 3) + ((lane >> 5) << 2);
      int col = wn * 96 + nf * 32 + (lane & 31);
      KQV[(size_t)row * 192 + col] = (__bf16)acc[nf][r];
    }
  }
#undef LOADA
#undef GLOADW
#undef MMA
}

// ---------------------------------------------------------------------------
// Kernel 2: causal attention per batch. 256 blocks (= 128 batches x 2 halves)
// x 256 threads (4 waves). Wave owns 32 q-rows. Swapped QK^T -> lane-local softmax.
// ---------------------------------------------------------------------------
__launch_bounds__(256, 1)
__global__ void attn_kernel(const __bf16* __restrict__ KQV, float* __restrict__ out) {
  __shared__ uint4 lds4[81920 / 16];  // K:[256][64] 32KB | Vt:[64][256] 32KB | Q:[128][64] 16KB
  char* Klds = (char*)lds4;
  char* Vlds = (char*)lds4 + 32768;
  char* Qlds = (char*)lds4 + 65536;

  const int tid = threadIdx.x;
  const int lane = tid & 63;
  const int wave = tid >> 6;  // 0..3
  const int b = blockIdx.x >> 1;
  const int half = blockIdx.x & 1;
  const int bt0 = half * 128;
  const size_t base = (size_t)b * 256 * 192;

  {
    int s = tid;
    const uint4* src = (const uint4*)(KQV + base + (size_t)s * 192 + 64);
#pragma unroll
    for (int i = 0; i < 8; i++) {
      uint4 v = src[i];
      int byte = s * 128 + ((i * 16) ^ ((s & 7) << 4));
      *(uint4*)(Klds + byte) = v;
    }
  }
  {
    int s = tid;
    const uint4* src = (const uint4*)(KQV + base + (size_t)s * 192 + 128);
#pragma unroll
    for (int i = 0; i < 8; i++) {
      uint4 v = src[i];
      const ushort* e = (const ushort*)&v;
#pragma unroll
      for (int j = 0; j < 8; j++) {
        int h = i * 8 + j;
        int byte = h * 512 + ((s * 2) ^ ((h & 7) << 4));
        *(ushort*)(Vlds + byte) = e[j];
      }
    }
  }
#pragma unroll
  for (int i = 0; i < 4; i++) {
    int c = tid + i * 256;
    int r = c >> 3, cc = c & 7;
    uint4 v = *(const uint4*)(KQV + base + (size_t)(bt0 + r) * 192 + cc * 8);
    int byte = r * 128 + ((cc * 16) ^ ((r & 7) << 4));
    *(uint4*)(Qlds + byte) = v;
  }
  __syncthreads();

  const int t0 = bt0 + wave * 32;
  const int tg = t0 + (lane & 31);
  const int nf = (t0 >> 5) + 1;

  f32x16 sacc[8];
#pragma unroll
  for (int sf = 0; sf < 8; sf++) {
    f32x16 sv = zero16();
    if (sf < nf) {
#pragma unroll
      for (int ks = 0; ks < 4; ks++) {
        int kbyte = ks * 32 + ((lane >> 5) << 4);
        int krow = sf * 32 + (lane & 31);
        v8bf a = *(const v8bf*)(Klds + krow * 128 + (kbyte ^ ((krow & 7) << 4)));
        int qrow = wave * 32 + (lane & 31);
        v8bf bq = *(const v8bf*)(Qlds + qrow * 128 + (kbyte ^ ((qrow & 7) << 4)));
        sv = __builtin_amdgcn_mfma_f32_32x32x16_bf16(a, bq, sv, 0, 0, 0);
      }
    }
    sacc[sf] = sv;
  }

  float m = -1e30f;
#pragma unroll
  for (int sf = 0; sf < 8; sf++) {
    if (sf < nf) {
#pragma unroll
      for (int r = 0; r < 16; r++) {
        int sg = sf * 32 + (r & 3) + ((r >> 2) << 3) + ((lane >> 5) << 2);
        float v = sacc[sf][r] * 0.125f;
        v = (sg > tg) ? -1e30f : v;
        sacc[sf][r] = v;
        m = fmaxf(m, v);
      }
    }
  }
  m = fmaxf(m, __shfl_xor(m, 32, 64));
  float l = 0.f;
#pragma unroll
  for (int sf = 0; sf < 8; sf++) {
    if (sf < nf) {
#pragma unroll
      for (int r = 0; r < 16; r++) {
        float p = __expf(sacc[sf][r] - m);
        sacc[sf][r] = p;
        l += p;
      }
    }
  }
  l += __shfl_xor(l, 32, 64);
  float inv = 1.0f / l;

  f32x16 oacc[2];
  oacc[0] = zero16();
  oacc[1] = zero16();
  const bool hiLane = (lane >= 32);
#pragma unroll
  for (int sf = 0; sf < 8; sf++) {
    if (sf < nf) {
      uint w[8], ow[8];
#pragma unroll
      for (int q = 0; q < 4; q++) {
        w[2 * q]     = pack_bf16(sacc[sf][4 * q] * inv,     sacc[sf][4 * q + 1] * inv);
        w[2 * q + 1] = pack_bf16(sacc[sf][4 * q + 2] * inv, sacc[sf][4 * q + 3] * inv);
      }
#pragma unroll
      for (int i = 0; i < 8; i++) ow[i] = (uint)__shfl_xor((int)w[i], 32, 64);
#pragma unroll
      for (int ks = 0; ks < 2; ks++) {
        int bse = 4 * ks;
        union { uint u[4]; v8bf v; } A;
        A.u[0] = hiLane ? ow[bse + 2] : w[bse + 0];
        A.u[1] = hiLane ? ow[bse + 3] : w[bse + 1];
        A.u[2] = hiLane ? w[bse + 2] : ow[bse + 0];
        A.u[3] = hiLane ? w[bse + 3] : ow[bse + 1];
        int sbyte0 = (sf * 32 + ks * 16) * 2 + ((lane >> 5) << 4);
#pragma unroll
        for (int hf = 0; hf < 2; hf++) {
          int vrow = hf * 32 + (lane & 31);
          v8bf bv = *(const v8bf*)(Vlds + vrow * 512 + (sbyte0 ^ ((vrow & 7) << 4)));
          oacc[hf] = __builtin_amdgcn_mfma_f32_32x32x16_bf16(A.v, bv, oacc[hf], 0, 0, 0);
        }
      }
    }
  }

#pragma unroll
  for (int hf = 0; hf < 2; hf++) {
#pragma unroll
    for (int r = 0; r < 16; r++) {
      int t = t0 + (r & 3) + ((r >> 2) << 3) + ((lane >> 5) << 2);
      int h = hf * 32 + (lane & 31);
      out[((size_t)b * 256 + t) * 64 + h] = oacc[hf][r];
    }
  }
}

// ---------------------------------------------------------------------------
extern "C" void kernel_launch(void* const* d_in, const int* in_sizes, int n_in,
                              void* d_out, int out_size, void* d_ws, size_t ws_size,
                              hipStream_t stream) {
  const float* x  = (const float*)d_in[0];
  const float* Wk = (const float*)d_in[1];
  const float* Wq = (const float*)d_in[2];
  const float* Wv = (const float*)d_in[3];
  float* out = (float*)d_out;

  // workspace: KQV bf16 [32768][192] (12.58 MB), then pre-swizzled Wt (384 KB)
  __bf16* KQV = (__bf16*)d_ws;
  char* Wt_s  = (char*)d_ws + (size_t)32768 * 192 * 2;

  prep_wt<<<48, 256, 0, stream>>>(Wq, Wk, Wv, Wt_s);
  proj_kernel<<<512, 256, 0, stream>>>(x, Wt_s, KQV);
  attn_kernel<<<256, 256, 0, stream>>>(KQV, out);
}

// Round 5
// 46.741 us; speedup vs baseline: 1.5252x; 1.3999x over previous
//
#include <hip/hip_runtime.h>
#include <hip/hip_bf16.h>

typedef __bf16 v8bf __attribute__((ext_vector_type(8)));
typedef float f32x16 __attribute__((ext_vector_type(16)));
typedef unsigned int uint;
typedef unsigned short ushort;

#define GLOAD16(gsrc, ldst)                                                       \
  __builtin_amdgcn_global_load_lds(                                               \
      (const __attribute__((address_space(1))) unsigned int*)(gsrc),              \
      (__attribute__((address_space(3))) unsigned int*)(ldst), 16, 0, 0)

__device__ inline f32x16 zero16() {
  f32x16 z;
#pragma unroll
  for (int i = 0; i < 16; i++) z[i] = 0.f;
  return z;
}

__device__ inline uint pack_bf16(float a, float b) {
  union { __bf16 h[2]; uint u; } c;
  c.h[0] = (__bf16)a;
  c.h[1] = (__bf16)b;
  return c.u;
}

// ---------------------------------------------------------------------------
// Kernel 0: Wt_s = transpose of [Wq|Wk|Wv] -> bf16, PRE-SWIZZLED:
// element (n,k) at byte n*2048 + (k>>6)*128 + (((k&63)*2) ^ ((n&7)<<4)).
// Linear global_load_lds of a 128B row-chunk then lands XOR-swizzled in LDS.
// ---------------------------------------------------------------------------
__global__ void prep_wt(const float* __restrict__ Wq, const float* __restrict__ Wk,
                        const float* __restrict__ Wv, char* __restrict__ Wt_s) {
  __shared__ __bf16 tile[64][74];
  const int mat = blockIdx.x >> 4;
  const int c0 = (blockIdx.x & 15) * 64;
  const float* src = (mat == 0) ? Wq : (mat == 1) ? Wk : Wv;
  const int t = threadIdx.x;  // 256 threads
  {
    const int r = t >> 2;
    const int ch = (t & 3) * 16;
    const float4* s4 = (const float4*)(src + (size_t)(c0 + r) * 64 + ch);
#pragma unroll
    for (int j = 0; j < 4; j++) {
      float4 f = s4[j];
      tile[r][ch + 4 * j + 0] = (__bf16)f.x;
      tile[r][ch + 4 * j + 1] = (__bf16)f.y;
      tile[r][ch + 4 * j + 2] = (__bf16)f.z;
      tile[r][ch + 4 * j + 3] = (__bf16)f.w;
    }
  }
  __syncthreads();
  const int h = t >> 2;
  const int cc = (t & 3) * 16;
  union { __bf16 o[16]; uint4 u[2]; } pk;
#pragma unroll
  for (int j = 0; j < 16; j++) pk.o[j] = tile[cc + j][h];
  const int n = mat * 64 + h;
  char* base = Wt_s + (size_t)n * 2048 + (c0 >> 6) * 128;
  const int bc = cc * 2;
  *(uint4*)(base + ((bc) ^ ((n & 7) << 4))) = pk.u[0];
  *(uint4*)(base + ((bc + 16) ^ ((n & 7) << 4))) = pk.u[1];
}

// ---------------------------------------------------------------------------
// Kernel 1: KQV[32768][192] = x * W. 512 blocks x 256 threads, 2 blocks/CU.
// Block tile 64x192; wave tile 32x96; BK=64. A: coalesced float4 -> regs ->
// bf16 -> swizzled LDS. W: global_load_lds from pre-swizzled Wt_s.
// Double-buffered, ONE barrier per K-step, loads issued before MFMA.
// ---------------------------------------------------------------------------
__launch_bounds__(256, 2)
__global__ void proj_kernel(const float* __restrict__ x, const char* __restrict__ Wt_s,
                            __bf16* __restrict__ KQV) {
  __shared__ char lds[65536];
  char* A0 = lds;            // [64][128B] swizzled, 8 KB
  char* A1 = lds + 8192;
  char* W0 = lds + 16384;    // [192][128B] swizzled, 24 KB
  char* W1 = lds + 40960;

  const int tid = threadIdx.x;
  const int lane = tid & 63;
  const int wave = tid >> 6;  // 0..3
  const int wm = wave >> 1;
  const int wn = wave & 1;
  const int row0 = blockIdx.x * 64;

  // A staging: thread owns row sr, 16 contiguous floats starting at sc*16
  const int sr = tid >> 2;
  const int sc = tid & 3;
  const float4* xp = (const float4*)(x + (size_t)(row0 + sr) * 1024 + sc * 16);

  f32x16 acc[3];
#pragma unroll
  for (int i = 0; i < 3; i++) acc[i] = zero16();

  float4 rA[4], rB[4];

#define LOADA(rr, t)                                                              \
  {                                                                               \
    _Pragma("unroll") for (int j = 0; j < 4; j++) rr[j] = xp[(t) * 16 + j];       \
  }

#define GW(t, Wbuf)                                                               \
  {                                                                               \
    _Pragma("unroll") for (int j = 0; j < 6; j++) {                               \
      int idx = wave * 64 + j * 256 + lane;                                       \
      GLOAD16(Wt_s + (size_t)(idx >> 3) * 2048 + (t) * 128 + (idx & 7) * 16,      \
              Wbuf + wave * 1024 + j * 4096);                                     \
    }                                                                             \
  }

#define CVTWRITE(rr, Abuf)                                                        \
  {                                                                               \
    union { __bf16 h[16]; uint4 u[2]; } cv;                                       \
    _Pragma("unroll") for (int j = 0; j < 4; j++) {                               \
      cv.h[4 * j + 0] = (__bf16)rr[j].x;                                          \
      cv.h[4 * j + 1] = (__bf16)rr[j].y;                                          \
      cv.h[4 * j + 2] = (__bf16)rr[j].z;                                          \
      cv.h[4 * j + 3] = (__bf16)rr[j].w;                                          \
    }                                                                             \
    *(uint4*)(Abuf + sr * 128 + ((sc * 32) ^ ((sr & 7) << 4))) = cv.u[0];         \
    *(uint4*)(Abuf + sr * 128 + ((sc * 32 + 16) ^ ((sr & 7) << 4))) = cv.u[1];    \
  }

#define MMA(Abuf, Wbuf)                                                           \
  {                                                                               \
    _Pragma("unroll") for (int ks = 0; ks < 4; ks++) {                            \
      int arow = wm * 32 + (lane & 31);                                           \
      int kb = ks * 32 + ((lane >> 5) << 4);                                      \
      v8bf av = *(const v8bf*)(Abuf + arow * 128 + (kb ^ ((arow & 7) << 4)));     \
      _Pragma("unroll") for (int nf = 0; nf < 3; nf++) {                          \
        int brow = wn * 96 + nf * 32 + (lane & 31);                               \
        v8bf bv = *(const v8bf*)(Wbuf + brow * 128 + (kb ^ ((brow & 7) << 4)));   \
        acc[nf] = __builtin_amdgcn_mfma_f32_32x32x16_bf16(av, bv, acc[nf], 0, 0, 0); \
      }                                                                           \
    }                                                                             \
  }

  // prologue
  GW(0, W0);
  LOADA(rA, 0);
  CVTWRITE(rA, A0);
  __syncthreads();

  for (int t = 0; t < 16; t += 2) {
    GW(t + 1, W1);
    LOADA(rB, t + 1);
    __builtin_amdgcn_sched_barrier(0);
    MMA(A0, W0);
    CVTWRITE(rB, A1);
    __syncthreads();
    if (t + 2 < 16) {
      GW(t + 2, W0);
      LOADA(rA, t + 2);
    }
    __builtin_amdgcn_sched_barrier(0);
    MMA(A1, W1);
    if (t + 2 < 16) {
      CVTWRITE(rA, A0);
      __syncthreads();
    }
  }

  // epilogue: write bf16 KQV
#pragma unroll
  for (int nf = 0; nf < 3; nf++) {
#pragma unroll
    for (int r = 0; r < 16; r++) {
      int row = row0 + wm * 32 + (r & 3) + ((r >> 2) << 3) + ((lane >> 5) << 2);
      int col = wn * 96 + nf * 32 + (lane & 31);
      KQV[(size_t)row * 192 + col] = (__bf16)acc[nf][r];
    }
  }
#undef LOADA
#undef GW
#undef CVTWRITE
#undef MMA
}

// ---------------------------------------------------------------------------
// Kernel 2: causal attention per batch. 256 blocks (= 128 batches x 2 halves)
// x 256 threads (4 waves). Wave owns 32 q-rows. Swapped QK^T -> lane-local softmax.
// ---------------------------------------------------------------------------
__launch_bounds__(256, 1)
__global__ void attn_kernel(const __bf16* __restrict__ KQV, float* __restrict__ out) {
  __shared__ uint4 lds4[81920 / 16];  // K:[256][64] 32KB | Vt:[64][256] 32KB | Q:[128][64] 16KB
  char* Klds = (char*)lds4;
  char* Vlds = (char*)lds4 + 32768;
  char* Qlds = (char*)lds4 + 65536;

  const int tid = threadIdx.x;
  const int lane = tid & 63;
  const int wave = tid >> 6;  // 0..3
  const int b = blockIdx.x >> 1;
  const int half = blockIdx.x & 1;
  const int bt0 = half * 128;
  const size_t base = (size_t)b * 256 * 192;

  {
    int s = tid;
    const uint4* src = (const uint4*)(KQV + base + (size_t)s * 192 + 64);
#pragma unroll
    for (int i = 0; i < 8; i++) {
      uint4 v = src[i];
      int byte = s * 128 + ((i * 16) ^ ((s & 7) << 4));
      *(uint4*)(Klds + byte) = v;
    }
  }
  {
    int s = tid;
    const uint4* src = (const uint4*)(KQV + base + (size_t)s * 192 + 128);
#pragma unroll
    for (int i = 0; i < 8; i++) {
      uint4 v = src[i];
      const ushort* e = (const ushort*)&v;
#pragma unroll
      for (int j = 0; j < 8; j++) {
        int h = i * 8 + j;
        int byte = h * 512 + ((s * 2) ^ ((h & 7) << 4));
        *(ushort*)(Vlds + byte) = e[j];
      }
    }
  }
#pragma unroll
  for (int i = 0; i < 4; i++) {
    int c = tid + i * 256;
    int r = c >> 3, cc = c & 7;
    uint4 v = *(const uint4*)(KQV + base + (size_t)(bt0 + r) * 192 + cc * 8);
    int byte = r * 128 + ((cc * 16) ^ ((r & 7) << 4));
    *(uint4*)(Qlds + byte) = v;
  }
  __syncthreads();

  const int t0 = bt0 + wave * 32;
  const int tg = t0 + (lane & 31);
  const int nf = (t0 >> 5) + 1;

  f32x16 sacc[8];
#pragma unroll
  for (int sf = 0; sf < 8; sf++) {
    f32x16 sv = zero16();
    if (sf < nf) {
#pragma unroll
      for (int ks = 0; ks < 4; ks++) {
        int kbyte = ks * 32 + ((lane >> 5) << 4);
        int krow = sf * 32 + (lane & 31);
        v8bf a = *(const v8bf*)(Klds + krow * 128 + (kbyte ^ ((krow & 7) << 4)));
        int qrow = wave * 32 + (lane & 31);
        v8bf bq = *(const v8bf*)(Qlds + qrow * 128 + (kbyte ^ ((qrow & 7) << 4)));
        sv = __builtin_amdgcn_mfma_f32_32x32x16_bf16(a, bq, sv, 0, 0, 0);
      }
    }
    sacc[sf] = sv;
  }

  float m = -1e30f;
#pragma unroll
  for (int sf = 0; sf < 8; sf++) {
    if (sf < nf) {
#pragma unroll
      for (int r = 0; r < 16; r++) {
        int sg = sf * 32 + (r & 3) + ((r >> 2) << 3) + ((lane >> 5) << 2);
        float v = sacc[sf][r] * 0.125f;
        v = (sg > tg) ? -1e30f : v;
        sacc[sf][r] = v;
        m = fmaxf(m, v);
      }
    }
  }
  m = fmaxf(m, __shfl_xor(m, 32, 64));
  float l = 0.f;
#pragma unroll
  for (int sf = 0; sf < 8; sf++) {
    if (sf < nf) {
#pragma unroll
      for (int r = 0; r < 16; r++) {
        float p = __expf(sacc[sf][r] - m);
        sacc[sf][r] = p;
        l += p;
      }
    }
  }
  l += __shfl_xor(l, 32, 64);
  float inv = 1.0f / l;

  f32x16 oacc[2];
  oacc[0] = zero16();
  oacc[1] = zero16();
  const bool hiLane = (lane >= 32);
#pragma unroll
  for (int sf = 0; sf < 8; sf++) {
    if (sf < nf) {
      uint w[8], ow[8];
#pragma unroll
      for (int q = 0; q < 4; q++) {
        w[2 * q]     = pack_bf16(sacc[sf][4 * q] * inv,     sacc[sf][4 * q + 1] * inv);
        w[2 * q + 1] = pack_bf16(sacc[sf][4 * q + 2] * inv, sacc[sf][4 * q + 3] * inv);
      }
#pragma unroll
      for (int i = 0; i < 8; i++) ow[i] = (uint)__shfl_xor((int)w[i], 32, 64);
#pragma unroll
      for (int ks = 0; ks < 2; ks++) {
        int bse = 4 * ks;
        union { uint u[4]; v8bf v; } A;
        A.u[0] = hiLane ? ow[bse + 2] : w[bse + 0];
        A.u[1] = hiLane ? ow[bse + 3] : w[bse + 1];
        A.u[2] = hiLane ? w[bse + 2] : ow[bse + 0];
        A.u[3] = hiLane ? w[bse + 3] : ow[bse + 1];
        int sbyte0 = (sf * 32 + ks * 16) * 2 + ((lane >> 5) << 4);
#pragma unroll
        for (int hf = 0; hf < 2; hf++) {
          int vrow = hf * 32 + (lane & 31);
          v8bf bv = *(const v8bf*)(Vlds + vrow * 512 + (sbyte0 ^ ((vrow & 7) << 4)));
          oacc[hf] = __builtin_amdgcn_mfma_f32_32x32x16_bf16(A.v, bv, oacc[hf], 0, 0, 0);
        }
      }
    }
  }

#pragma unroll
  for (int hf = 0; hf < 2; hf++) {
#pragma unroll
    for (int r = 0; r < 16; r++) {
      int t = t0 + (r & 3) + ((r >> 2) << 3) + ((lane >> 5) << 2);
      int h = hf * 32 + (lane & 31);
      out[((size_t)b * 256 + t) * 64 + h] = oacc[hf][r];
    }
  }
}

// ---------------------------------------------------------------------------
extern "C" void kernel_launch(void* const* d_in, const int* in_sizes, int n_in,
                              void* d_out, int out_size, void* d_ws, size_t ws_size,
                              hipStream_t stream) {
  const float* x  = (const float*)d_in[0];
  const float* Wk = (const float*)d_in[1];
  const float* Wq = (const float*)d_in[2];
  const float* Wv = (const float*)d_in[3];
  float* out = (float*)d_out;

  // workspace: KQV bf16 [32768][192] (12.58 MB), then pre-swizzled Wt (384 KB)
  __bf16* KQV = (__bf16*)d_ws;
  char* Wt_s  = (char*)d_ws + (size_t)32768 * 192 * 2;

  prep_wt<<<48, 256, 0, stream>>>(Wq, Wk, Wv, Wt_s);
  proj_kernel<<<512, 256, 0, stream>>>(x, Wt_s, KQV);
  attn_kernel<<<256, 256, 0, stream>>>(KQV, out);
}